// Round 1
// baseline (1505.360 us; speedup 1.0000x reference)
//
#include <hip/hip_runtime.h>

#define AS1 __attribute__((address_space(1)))
#define AS3 __attribute__((address_space(3)))

typedef short short8 __attribute__((ext_vector_type(8)));
typedef float floatx4 __attribute__((ext_vector_type(4)));

#define NTOK 262144
#define NWIN 4096
#define QKV_SCALE 0.17677669529663687f

__device__ __forceinline__ unsigned short f2bf(float f) {
  unsigned u = __builtin_bit_cast(unsigned, f);
  u += 0x7fffu + ((u >> 16) & 1u);          // round-to-nearest-even
  return (unsigned short)(u >> 16);
}

__device__ __forceinline__ void gl_lds16(const void* g, void* l) {
  __builtin_amdgcn_global_load_lds((AS1 void*)g, (AS3 void*)l, 16, 0, 0);
}

// ---------------- generic GEMM core ----------------
// C[m0..m0+128, n0..n0+64] = A(M x K, row-major bf16) * W(N x K, row-major bf16)^T
// 256 threads = 4 waves; wave w owns rows [w*32, w*32+32); acc[2][4] of 16x16 tiles.
// LDS staging via global_load_lds (linear dest) with XOR-swizzled source so the
// swizzled ds_read_b128 fragment reads are bank-conflict-light.
template <int K>
__device__ __forceinline__ void gemm_core(const unsigned short* __restrict__ A,
                                          const unsigned short* __restrict__ W,
                                          int m0, int n0,
                                          unsigned short* smA, unsigned short* smB,
                                          floatx4 acc[2][4]) {
  const int t = threadIdx.x;
  const int lane = t & 63;
  const int w = t >> 6;
  const int kg = lane >> 4;
  const int l15 = lane & 15;
  const int rA = t >> 2;   // 0..63
  const int q = t & 3;     // 16B slot

#pragma unroll
  for (int i = 0; i < 2; i++)
#pragma unroll
    for (int j = 0; j < 4; j++) acc[i][j] = floatx4{0.f, 0.f, 0.f, 0.f};

  for (int k0 = 0; k0 < K; k0 += 32) {
    __syncthreads();
    {
      const int s0 = (q ^ ((rA >> 1) & 3)) << 3;           // swizzled k-slot (elements)
      gl_lds16(A + (m0 + rA) * K + k0 + s0, (char*)smA + t * 16);
      const int r1 = rA + 64;
      const int s1 = (q ^ ((r1 >> 1) & 3)) << 3;
      gl_lds16(A + (m0 + r1) * K + k0 + s1, (char*)smA + 4096 + t * 16);
      gl_lds16(W + (n0 + rA) * K + k0 + s0, (char*)smB + t * 16);
    }
    asm volatile("s_waitcnt vmcnt(0)" ::: "memory");
    __syncthreads();

    short8 a[2], b[4];
#pragma unroll
    for (int rb = 0; rb < 2; rb++) {
      int row = w * 32 + rb * 16 + l15;
      a[rb] = *(const short8*)((const char*)smA + row * 64 + ((kg ^ ((row >> 1) & 3)) << 4));
    }
#pragma unroll
    for (int cb = 0; cb < 4; cb++) {
      int col = cb * 16 + l15;
      b[cb] = *(const short8*)((const char*)smB + col * 64 + ((kg ^ ((col >> 1) & 3)) << 4));
    }
#pragma unroll
    for (int rb = 0; rb < 2; rb++)
#pragma unroll
      for (int cb = 0; cb < 4; cb++)
        acc[rb][cb] = __builtin_amdgcn_mfma_f32_16x16x32_bf16(a[rb], b[cb], acc[rb][cb], 0, 0, 0);
  }
}

// ---------------- small utility kernels ----------------
__global__ __launch_bounds__(256) void k_wcvt(const float* __restrict__ src,
                                              unsigned short* __restrict__ dst, int n) {
  int i = blockIdx.x * 256 + threadIdx.x;
  if (i < n) dst[i] = f2bf(src[i]);
}

// bias table: btab[h][r][c] = rpb[rel_idx(r,c)*6 + h], 6*64*64 entries
__global__ __launch_bounds__(256) void k_bias(const float* __restrict__ rpb,
                                              float* __restrict__ btab) {
  int i = blockIdx.x * 256 + threadIdx.x;   // < 24576
  int h = i >> 12, rc = i & 4095, r = rc >> 6, c = rc & 63;
  int dd = (r >> 4) - (c >> 4) + 3;
  int dh = ((r >> 2) & 3) - ((c >> 2) & 3) + 3;
  int dw = (r & 3) - (c & 3) + 3;
  int rel = dd * 49 + dh * 7 + dw;
  btab[i] = rpb[rel * 6 + h];
}

// LN1 + roll(-2,-2,-2) + window partition -> xw (window-ordered rows, bf16)
__global__ __launch_bounds__(256) void k_ln1(const float* __restrict__ x,
                                             const float* __restrict__ g,
                                             const float* __restrict__ b,
                                             unsigned short* __restrict__ xw) {
  int w = threadIdx.x >> 6, lane = threadIdx.x & 63;
  int id = blockIdx.x * 4 + w;               // windowed token id
  int win = id >> 6, tok = id & 63;
  int bd = win >> 8, bh = (win >> 4) & 15, bw = win & 15;
  int td = tok >> 4, th = (tok >> 2) & 3, tw = tok & 3;
  int sd = (bd * 4 + td + 2) & 63, sh = (bh * 4 + th + 2) & 63, sw = (bw * 4 + tw + 2) & 63;
  const float* row = x + ((sd * 64 + sh) * 64 + sw) * 192;
  float v0 = row[lane], v1 = row[lane + 64], v2 = row[lane + 128];
  float s = v0 + v1 + v2, ss = v0 * v0 + v1 * v1 + v2 * v2;
#pragma unroll
  for (int o = 1; o < 64; o <<= 1) { s += __shfl_xor(s, o); ss += __shfl_xor(ss, o); }
  float mean = s * (1.0f / 192.0f);
  float var = ss * (1.0f / 192.0f) - mean * mean;
  float inv = rsqrtf(var + 1e-5f);
  unsigned short* orow = xw + id * 192;
  orow[lane]       = f2bf((v0 - mean) * inv * g[lane] + b[lane]);
  orow[lane + 64]  = f2bf((v1 - mean) * inv * g[lane + 64] + b[lane + 64]);
  orow[lane + 128] = f2bf((v2 - mean) * inv * g[lane + 128] + b[lane + 128]);
}

// LN2: read x_new (f32, = d_out), write xn bf16 (spatial token order)
__global__ __launch_bounds__(256) void k_ln2(const float* __restrict__ xin,
                                             const float* __restrict__ g,
                                             const float* __restrict__ b,
                                             unsigned short* __restrict__ xn) {
  int w = threadIdx.x >> 6, lane = threadIdx.x & 63;
  int id = blockIdx.x * 4 + w;
  const float* row = xin + id * 192;
  float v0 = row[lane], v1 = row[lane + 64], v2 = row[lane + 128];
  float s = v0 + v1 + v2, ss = v0 * v0 + v1 * v1 + v2 * v2;
#pragma unroll
  for (int o = 1; o < 64; o <<= 1) { s += __shfl_xor(s, o); ss += __shfl_xor(ss, o); }
  float mean = s * (1.0f / 192.0f);
  float var = ss * (1.0f / 192.0f) - mean * mean;
  float inv = rsqrtf(var + 1e-5f);
  unsigned short* orow = xn + id * 192;
  orow[lane]       = f2bf((v0 - mean) * inv * g[lane] + b[lane]);
  orow[lane + 64]  = f2bf((v1 - mean) * inv * g[lane + 64] + b[lane + 64]);
  orow[lane + 128] = f2bf((v2 - mean) * inv * g[lane + 128] + b[lane + 128]);
}

// ---------------- GEMM kernels ----------------
__global__ __launch_bounds__(256) void k_qkv(const unsigned short* __restrict__ xw,
                                             const unsigned short* __restrict__ wq,
                                             const float* __restrict__ qkv_b,
                                             unsigned short* __restrict__ qb,
                                             unsigned short* __restrict__ kb,
                                             unsigned short* __restrict__ vb) {
  __shared__ __attribute__((aligned(16))) unsigned short smA[128 * 32];
  __shared__ __attribute__((aligned(16))) unsigned short smB[64 * 32];
  floatx4 acc[2][4];
  int m0 = blockIdx.x * 128, n0 = blockIdx.y * 64;
  gemm_core<192>(xw, wq, m0, n0, smA, smB, acc);
  int t = threadIdx.x, lane = t & 63, w = t >> 6, kg = lane >> 4, l15 = lane & 15;
#pragma unroll
  for (int rb = 0; rb < 2; rb++)
#pragma unroll
    for (int cb = 0; cb < 4; cb++) {
      int n = n0 + cb * 16 + l15;
      int sel = n / 192, rem = n % 192;
      int head = rem >> 5, d = rem & 31;
      float bias = qkv_b[n];
#pragma unroll
      for (int reg = 0; reg < 4; reg++) {
        int m = m0 + w * 32 + rb * 16 + kg * 4 + reg;
        int win = m >> 6, tok = m & 63;
        float v = acc[rb][cb][reg] + bias;
        if (sel == 0)      qb[((win * 6 + head) * 64 + tok) * 32 + d] = f2bf(v * QKV_SCALE);
        else if (sel == 1) kb[((win * 6 + head) * 64 + tok) * 32 + d] = f2bf(v);
        else               vb[((win * 6 + head) * 32 + d) * 64 + tok] = f2bf(v);  // V^T
      }
    }
}

__global__ __launch_bounds__(256) void k_proj(const unsigned short* __restrict__ ob,
                                              const unsigned short* __restrict__ wp,
                                              const float* __restrict__ pb,
                                              const float* __restrict__ x,
                                              float* __restrict__ out) {
  __shared__ __attribute__((aligned(16))) unsigned short smA[128 * 32];
  __shared__ __attribute__((aligned(16))) unsigned short smB[64 * 32];
  floatx4 acc[2][4];
  int m0 = blockIdx.x * 128, n0 = blockIdx.y * 64;
  gemm_core<192>(ob, wp, m0, n0, smA, smB, acc);
  int t = threadIdx.x, lane = t & 63, w = t >> 6, kg = lane >> 4, l15 = lane & 15;
#pragma unroll
  for (int rb = 0; rb < 2; rb++)
#pragma unroll
    for (int cb = 0; cb < 4; cb++) {
      int n = n0 + cb * 16 + l15;
      float bias = pb[n];
#pragma unroll
      for (int reg = 0; reg < 4; reg++) {
        int m = m0 + w * 32 + rb * 16 + kg * 4 + reg;
        int win = m >> 6, tok = m & 63;
        int bd = win >> 8, bh = (win >> 4) & 15, bw = win & 15;
        int td = tok >> 4, th = (tok >> 2) & 3, tw = tok & 3;
        int od = (bd * 4 + td + 2) & 63, oh = (bh * 4 + th + 2) & 63, ow = (bw * 4 + tw + 2) & 63;
        int orow = (od * 64 + oh) * 64 + ow;
        out[orow * 192 + n] = x[orow * 192 + n] + acc[rb][cb][reg] + bias;
      }
    }
}

__global__ __launch_bounds__(256) void k_fc1(const unsigned short* __restrict__ xn,
                                             const unsigned short* __restrict__ w1,
                                             const float* __restrict__ b1,
                                             unsigned short* __restrict__ h1, int mbase) {
  __shared__ __attribute__((aligned(16))) unsigned short smA[128 * 32];
  __shared__ __attribute__((aligned(16))) unsigned short smB[64 * 32];
  floatx4 acc[2][4];
  int m0 = mbase + blockIdx.x * 128, n0 = blockIdx.y * 64;
  gemm_core<192>(xn, w1, m0, n0, smA, smB, acc);
  int t = threadIdx.x, lane = t & 63, w = t >> 6, kg = lane >> 4, l15 = lane & 15;
#pragma unroll
  for (int rb = 0; rb < 2; rb++)
#pragma unroll
    for (int cb = 0; cb < 4; cb++) {
      int n = n0 + cb * 16 + l15;
      float bias = b1[n];
#pragma unroll
      for (int reg = 0; reg < 4; reg++) {
        int mr = blockIdx.x * 128 + w * 32 + rb * 16 + kg * 4 + reg;  // chunk-relative
        float v = acc[rb][cb][reg] + bias;
        float gl = 0.5f * v * (1.0f + erff(v * 0.70710678118654752f));
        h1[mr * 768 + n] = f2bf(gl);
      }
    }
}

__global__ __launch_bounds__(256) void k_fc2(const unsigned short* __restrict__ h1,
                                             const unsigned short* __restrict__ w2,
                                             const float* __restrict__ b2,
                                             float* __restrict__ out, int mbase) {
  __shared__ __attribute__((aligned(16))) unsigned short smA[128 * 32];
  __shared__ __attribute__((aligned(16))) unsigned short smB[64 * 32];
  floatx4 acc[2][4];
  int m0 = blockIdx.x * 128, n0 = blockIdx.y * 64;   // m0 relative to h1 chunk
  gemm_core<768>(h1, w2, m0, n0, smA, smB, acc);
  int t = threadIdx.x, lane = t & 63, w = t >> 6, kg = lane >> 4, l15 = lane & 15;
#pragma unroll
  for (int rb = 0; rb < 2; rb++)
#pragma unroll
    for (int cb = 0; cb < 4; cb++) {
      int n = n0 + cb * 16 + l15;
      float bias = b2[n];
#pragma unroll
      for (int reg = 0; reg < 4; reg++) {
        int m = mbase + m0 + w * 32 + rb * 16 + kg * 4 + reg;
        out[m * 192 + n] = out[m * 192 + n] + acc[rb][cb][reg] + bias;
      }
    }
}

// ---------------- attention: 1 block / window, 1 wave / head ----------------
__global__ __launch_bounds__(384) void k_attn(const unsigned short* __restrict__ qb,
                                              const unsigned short* __restrict__ kb,
                                              const unsigned short* __restrict__ vb,
                                              const float* __restrict__ mask,
                                              const float* __restrict__ btab,
                                              unsigned short* __restrict__ ob) {
  __shared__ __attribute__((aligned(16))) unsigned short P[6][64][72];  // padded P rows
  int win = blockIdx.x;
  int h = threadIdx.x >> 6;        // head = wave id
  int lane = threadIdx.x & 63;
  int kg = lane >> 4, l15 = lane & 15;

  const short8* Q  = (const short8*)(qb + (win * 6 + h) * 2048);  // 64x32 bf16, pre-scaled
  const short8* Kf = (const short8*)(kb + (win * 6 + h) * 2048);
  const short8* Vt = (const short8*)(vb + (win * 6 + h) * 2048);  // V^T: 32x64

  short8 aQ[4], bK[4];
#pragma unroll
  for (int i = 0; i < 4; i++) aQ[i] = Q[(i * 16 + l15) * 4 + kg];
#pragma unroll
  for (int j = 0; j < 4; j++) bK[j] = Kf[(j * 16 + l15) * 4 + kg];

  floatx4 sc[4][4];
#pragma unroll
  for (int i = 0; i < 4; i++)
#pragma unroll
    for (int j = 0; j < 4; j++) {
      floatx4 z = floatx4{0.f, 0.f, 0.f, 0.f};
      sc[i][j] = __builtin_amdgcn_mfma_f32_16x16x32_bf16(aQ[i], bK[j], z, 0, 0, 0);
    }

  const float* mrow = mask + win * 4096;
  const float* brow = btab + h * 4096;
#pragma unroll
  for (int i = 0; i < 4; i++) {
#pragma unroll
    for (int reg = 0; reg < 4; reg++) {
      int r = i * 16 + kg * 4 + reg;
      float e[4];
      float rm = -1e30f;
#pragma unroll
      for (int j = 0; j < 4; j++) {
        int c = j * 16 + l15;
        float v = sc[i][j][reg] + brow[r * 64 + c] + mrow[r * 64 + c];
        e[j] = v;
        rm = fmaxf(rm, v);
      }
      rm = fmaxf(rm, __shfl_xor(rm, 1));
      rm = fmaxf(rm, __shfl_xor(rm, 2));
      rm = fmaxf(rm, __shfl_xor(rm, 4));
      rm = fmaxf(rm, __shfl_xor(rm, 8));
      float rs = 0.f;
#pragma unroll
      for (int j = 0; j < 4; j++) { e[j] = __expf(e[j] - rm); rs += e[j]; }
      rs += __shfl_xor(rs, 1); rs += __shfl_xor(rs, 2);
      rs += __shfl_xor(rs, 4); rs += __shfl_xor(rs, 8);
      float inv = 1.0f / rs;
#pragma unroll
      for (int j = 0; j < 4; j++) P[h][r][j * 16 + l15] = f2bf(e[j] * inv);
    }
  }
  __syncthreads();

  floatx4 o[4][2];
#pragma unroll
  for (int rb = 0; rb < 4; rb++)
#pragma unroll
    for (int db = 0; db < 2; db++) o[rb][db] = floatx4{0.f, 0.f, 0.f, 0.f};

#pragma unroll
  for (int kk = 0; kk < 2; kk++) {
    short8 pv[4];
#pragma unroll
    for (int rb = 0; rb < 4; rb++)
      pv[rb] = *(const short8*)(&P[h][rb * 16 + l15][kk * 32 + kg * 8]);
#pragma unroll
    for (int db = 0; db < 2; db++) {
      short8 vv = Vt[(db * 16 + l15) * 8 + kk * 4 + kg];
#pragma unroll
      for (int rb = 0; rb < 4; rb++)
        o[rb][db] = __builtin_amdgcn_mfma_f32_16x16x32_bf16(pv[rb], vv, o[rb][db], 0, 0, 0);
    }
  }

#pragma unroll
  for (int rb = 0; rb < 4; rb++)
#pragma unroll
    for (int db = 0; db < 2; db++)
#pragma unroll
      for (int reg = 0; reg < 4; reg++) {
        int tok = rb * 16 + kg * 4 + reg;
        int d = db * 16 + l15;
        ob[(win * 64 + tok) * 192 + h * 32 + d] = f2bf(o[rb][db][reg]);
      }
}

// ---------------- launch ----------------
extern "C" void kernel_launch(void* const* d_in, const int* in_sizes, int n_in,
                              void* d_out, int out_size, void* d_ws, size_t ws_size,
                              hipStream_t stream) {
  const float* x     = (const float*)d_in[0];
  const float* mask  = (const float*)d_in[1];
  const float* n1g   = (const float*)d_in[2];
  const float* n1b   = (const float*)d_in[3];
  const float* qkvw  = (const float*)d_in[4];
  const float* qkvb  = (const float*)d_in[5];
  const float* rpb   = (const float*)d_in[6];
  const float* projw = (const float*)d_in[7];
  const float* projb = (const float*)d_in[8];
  const float* n2g   = (const float*)d_in[9];
  const float* n2b   = (const float*)d_in[10];
  const float* fc1w  = (const float*)d_in[11];
  const float* fc1b  = (const float*)d_in[12];
  const float* fc2w  = (const float*)d_in[13];
  const float* fc2b  = (const float*)d_in[14];
  float* out = (float*)d_out;
  char* ws = (char*)d_ws;

  // workspace arena (~404 MB peak):
  // [0, 100.7MB):      xw (LN1 out) -> obuf (attn out) -> xn (LN2 out)   bf16
  // [100.7, 201.3MB):  qbuf -> h1 chunk (65536 x 768 bf16)
  // [201.3, 302MB):    kbuf
  // [302, 402.7MB):    vbuf (V^T)
  // [402.7MB, ...):    bf16 weights + bias table
  unsigned short* xw = (unsigned short*)(ws);
  unsigned short* qb = (unsigned short*)(ws + 100663296);
  unsigned short* kb = (unsigned short*)(ws + 201326592);
  unsigned short* vb = (unsigned short*)(ws + 301989888);
  unsigned short* h1 = qb;  // reuse after attention
  unsigned short* wq = (unsigned short*)(ws + 402653184);
  unsigned short* wp = wq + 110592;
  unsigned short* w1 = wp + 36864;
  unsigned short* w2 = w1 + 147456;
  float* btab = (float*)(ws + 402653184 + 884736);

  k_wcvt<<<dim3((110592 + 255) / 256), 256, 0, stream>>>(qkvw, wq, 110592);
  k_wcvt<<<dim3((36864 + 255) / 256), 256, 0, stream>>>(projw, wp, 36864);
  k_wcvt<<<dim3((147456 + 255) / 256), 256, 0, stream>>>(fc1w, w1, 147456);
  k_wcvt<<<dim3((147456 + 255) / 256), 256, 0, stream>>>(fc2w, w2, 147456);
  k_bias<<<dim3(96), 256, 0, stream>>>(rpb, btab);

  k_ln1<<<dim3(65536), 256, 0, stream>>>(x, n1g, n1b, xw);
  k_qkv<<<dim3(2048, 9), 256, 0, stream>>>(xw, wq, qkvb, qb, kb, vb);
  k_attn<<<dim3(4096), 384, 0, stream>>>(qb, kb, vb, mask, btab, xw /*obuf*/);
  k_proj<<<dim3(2048, 3), 256, 0, stream>>>(xw, wp, projb, x, out);
  k_ln2<<<dim3(65536), 256, 0, stream>>>(out, n2g, n2b, xw /*xn*/);
  for (int c = 0; c < 4; c++) {
    k_fc1<<<dim3(512, 12), 256, 0, stream>>>(xw, w1, fc1b, h1, c * 65536);
    k_fc2<<<dim3(512, 3), 256, 0, stream>>>(h1, w2, fc2b, out, c * 65536);
  }
}

// Round 2
// 1290.159 us; speedup vs baseline: 1.1668x; 1.1668x over previous
//
#include <hip/hip_runtime.h>

#define AS1 __attribute__((address_space(1)))
#define AS3 __attribute__((address_space(3)))

typedef short short8 __attribute__((ext_vector_type(8)));
typedef short short4v __attribute__((ext_vector_type(4)));
typedef float floatx4 __attribute__((ext_vector_type(4)));

#define QKV_SCALE 0.17677669529663687f

__device__ __forceinline__ unsigned short f2bf(float f) {
  unsigned u = __builtin_bit_cast(unsigned, f);
  u += 0x7fffu + ((u >> 16) & 1u);
  return (unsigned short)(u >> 16);
}

__device__ __forceinline__ void gl_lds16(const void* g, void* l) {
  __builtin_amdgcn_global_load_lds((AS1 void*)g, (AS3 void*)l, 16, 0, 0);
}

// Stage ITERS*256 16B-slots of a row-major bf16 tile (24 slots = 192 elems per row)
// into LDS, XOR-swizzling the SOURCE slot so swizzled ds_read_b128 reads are clean.
template <int ITERS>
__device__ __forceinline__ void stage_tile(const unsigned short* __restrict__ src, int rstride,
                                           unsigned short* lds) {
  const int t = threadIdx.x;
#pragma unroll
  for (int i = 0; i < ITERS; i++) {
    int D = i * 256 + t;
    int row = D / 24, sl = D - row * 24;
    int ss = sl ^ (row & 7);
    gl_lds16(src + row * rstride + ss * 8, (char*)lds + D * 16);
  }
}

// fragment read from a [R][192] bf16 LDS tile with the matching swizzle
__device__ __forceinline__ short8 frag192(const unsigned short* lds, int row, int ks, int kg) {
  return *(const short8*)((const char*)lds + row * 384 + ((((ks << 2) + kg) ^ (row & 7)) << 4));
}

// ---------------- small utility kernels ----------------
__global__ __launch_bounds__(256) void k_wcvt(const float* __restrict__ src,
                                              unsigned short* __restrict__ dst, int n) {
  int i = blockIdx.x * 256 + threadIdx.x;
  if (i < n) dst[i] = f2bf(src[i]);
}

__global__ __launch_bounds__(256) void k_bias(const float* __restrict__ rpb,
                                              float* __restrict__ btab) {
  int i = blockIdx.x * 256 + threadIdx.x;   // < 24576
  int h = i >> 12, rc = i & 4095, r = rc >> 6, c = rc & 63;
  int dd = (r >> 4) - (c >> 4) + 3;
  int dh = ((r >> 2) & 3) - ((c >> 2) & 3) + 3;
  int dw = (r & 3) - (c & 3) + 3;
  btab[i] = rpb[(dd * 49 + dh * 7 + dw) * 6 + h];
}

// ---------------- LN1 + QKV (A staged once, 9 n-chunks) ----------------
__global__ __launch_bounds__(256, 2) void k_qkv(const float* __restrict__ x,
                                                const float* __restrict__ g,
                                                const float* __restrict__ bb,
                                                const unsigned short* __restrict__ wq,
                                                const float* __restrict__ qkv_b,
                                                unsigned short* __restrict__ qb,
                                                unsigned short* __restrict__ kb,
                                                unsigned short* __restrict__ vb) {
  __shared__ __attribute__((aligned(16))) unsigned short smA[128 * 192];
  __shared__ __attribute__((aligned(16))) unsigned short smB[64 * 192];
  const int t = threadIdx.x;
  const int m0 = blockIdx.x * 128;

  // --- LN phase: 2 threads per row ---
  {
    int r = t >> 1, half = t & 1;
    int id = m0 + r, win = id >> 6, tok = id & 63;
    int bd = win >> 8, bh = (win >> 4) & 15, bw = win & 15;
    int sd = ((bd << 2) + (tok >> 4) + 2) & 63;
    int sh = ((bh << 2) + ((tok >> 2) & 3) + 2) & 63;
    int sw = ((bw << 2) + (tok & 3) + 2) & 63;
    const float4* rp = (const float4*)(x + ((sd * 64 + sh) * 64 + sw) * 192 + half * 96);
    float4 v[24];
#pragma unroll
    for (int j = 0; j < 24; j++) v[j] = rp[j];
    float s = 0.f, ss = 0.f;
#pragma unroll
    for (int j = 0; j < 24; j++) {
      s += v[j].x + v[j].y + v[j].z + v[j].w;
      ss += v[j].x * v[j].x + v[j].y * v[j].y + v[j].z * v[j].z + v[j].w * v[j].w;
    }
    s += __shfl_xor(s, 1);
    ss += __shfl_xor(ss, 1);
    float mean = s * (1.0f / 192.0f);
    float inv = rsqrtf(ss * (1.0f / 192.0f) - mean * mean + 1e-5f);
    const float4* gp = (const float4*)(g + half * 96);
    const float4* bp = (const float4*)(bb + half * 96);
#pragma unroll
    for (int j = 0; j < 12; j++) {
      float4 a0 = v[2 * j], a1 = v[2 * j + 1];
      float4 g0 = gp[2 * j], g1 = gp[2 * j + 1];
      float4 c0 = bp[2 * j], c1 = bp[2 * j + 1];
      short8 o;
      o[0] = (short)f2bf((a0.x - mean) * inv * g0.x + c0.x);
      o[1] = (short)f2bf((a0.y - mean) * inv * g0.y + c0.y);
      o[2] = (short)f2bf((a0.z - mean) * inv * g0.z + c0.z);
      o[3] = (short)f2bf((a0.w - mean) * inv * g0.w + c0.w);
      o[4] = (short)f2bf((a1.x - mean) * inv * g1.x + c1.x);
      o[5] = (short)f2bf((a1.y - mean) * inv * g1.y + c1.y);
      o[6] = (short)f2bf((a1.z - mean) * inv * g1.z + c1.z);
      o[7] = (short)f2bf((a1.w - mean) * inv * g1.w + c1.w);
      int sl = half * 12 + j;
      *(short8*)((char*)smA + r * 384 + ((sl ^ (r & 7)) << 4)) = o;
    }
  }

  const int lane = t & 63, w = t >> 6, kg = lane >> 4, l15 = lane & 15;
  short8 afr[2][6];
  floatx4 acc[2][4];

  for (int c = 0; c < 9; c++) {
    if (c) __syncthreads();
    stage_tile<6>(wq + c * 64 * 192, 192, smB);
    asm volatile("s_waitcnt vmcnt(0)" ::: "memory");
    __syncthreads();
    if (c == 0) {
#pragma unroll
      for (int rb = 0; rb < 2; rb++)
#pragma unroll
        for (int ks = 0; ks < 6; ks++)
          afr[rb][ks] = frag192(smA, w * 32 + rb * 16 + l15, ks, kg);
    }
#pragma unroll
    for (int rb = 0; rb < 2; rb++)
#pragma unroll
      for (int cb = 0; cb < 4; cb++) acc[rb][cb] = floatx4{0.f, 0.f, 0.f, 0.f};
#pragma unroll
    for (int ks = 0; ks < 6; ks++) {
      short8 b[4];
#pragma unroll
      for (int cb = 0; cb < 4; cb++) b[cb] = frag192(smB, cb * 16 + l15, ks, kg);
#pragma unroll
      for (int rb = 0; rb < 2; rb++)
#pragma unroll
        for (int cb = 0; cb < 4; cb++)
          acc[rb][cb] = __builtin_amdgcn_mfma_f32_16x16x32_bf16(afr[rb][ks], b[cb], acc[rb][cb], 0, 0, 0);
    }
    // epilogue: scatter q/k/v
#pragma unroll
    for (int cb = 0; cb < 4; cb++) {
      int n = c * 64 + cb * 16 + l15;
      int sel = n / 192, rem = n - sel * 192;
      int head = rem >> 5, d = rem & 31;
      float bias = qkv_b[n];
#pragma unroll
      for (int rb = 0; rb < 2; rb++) {
        int mb = m0 + w * 32 + rb * 16 + kg * 4;
        int win = mb >> 6, tk0 = mb & 63;
        if (sel == 2) {
          short4v pk;
#pragma unroll
          for (int reg = 0; reg < 4; reg++) pk[reg] = (short)f2bf(acc[rb][cb][reg] + bias);
          *(short4v*)(vb + ((win * 6 + head) * 32 + d) * 64 + tk0) = pk;
        } else {
#pragma unroll
          for (int reg = 0; reg < 4; reg++) {
            float v = acc[rb][cb][reg] + bias;
            if (sel == 0)
              qb[((win * 6 + head) * 64 + tk0 + reg) * 32 + d] = f2bf(v * QKV_SCALE);
            else
              kb[((win * 6 + head) * 64 + tk0 + reg) * 32 + d] = f2bf(v);
          }
        }
      }
    }
  }
}

// ---------------- attention: 1 block / window, 1 wave / head ----------------
__global__ __launch_bounds__(384) void k_attn(const unsigned short* __restrict__ qb,
                                              const unsigned short* __restrict__ kb,
                                              const unsigned short* __restrict__ vb,
                                              const float* __restrict__ btab,
                                              unsigned short* __restrict__ ob) {
  __shared__ __attribute__((aligned(16))) unsigned short P[6][64][72];
  int win = blockIdx.x;
  int h = threadIdx.x >> 6;
  int lane = threadIdx.x & 63;
  int kg = lane >> 4, l15 = lane & 15;

  // analytic shift mask: token segments differ on bit5/3/1 of r^c for boundary windows
  int mm = (((win >> 8) == 15) ? 32 : 0) | ((((win >> 4) & 15) == 15) ? 8 : 0) |
           (((win & 15) == 15) ? 2 : 0);

  const short8* Q = (const short8*)(qb + (win * 6 + h) * 2048);
  const short8* Kf = (const short8*)(kb + (win * 6 + h) * 2048);
  const short8* Vt = (const short8*)(vb + (win * 6 + h) * 2048);

  short8 aQ[4], bK[4];
#pragma unroll
  for (int i = 0; i < 4; i++) aQ[i] = Q[(i * 16 + l15) * 4 + kg];
#pragma unroll
  for (int j = 0; j < 4; j++) bK[j] = Kf[(j * 16 + l15) * 4 + kg];

  floatx4 sc[4][4];
#pragma unroll
  for (int i = 0; i < 4; i++)
#pragma unroll
    for (int j = 0; j < 4; j++) {
      floatx4 z = floatx4{0.f, 0.f, 0.f, 0.f};
      sc[i][j] = __builtin_amdgcn_mfma_f32_16x16x32_bf16(aQ[i], bK[j], z, 0, 0, 0);
    }

  const float* brow = btab + h * 4096;
#pragma unroll
  for (int i = 0; i < 4; i++) {
#pragma unroll
    for (int reg = 0; reg < 4; reg++) {
      int r = i * 16 + kg * 4 + reg;
      float e[4];
      float rm = -1e30f;
#pragma unroll
      for (int j = 0; j < 4; j++) {
        int cidx = j * 16 + l15;
        float mval = ((r ^ cidx) & mm) ? -100.0f : 0.0f;
        float v = sc[i][j][reg] + brow[r * 64 + cidx] + mval;
        e[j] = v;
        rm = fmaxf(rm, v);
      }
      rm = fmaxf(rm, __shfl_xor(rm, 1));
      rm = fmaxf(rm, __shfl_xor(rm, 2));
      rm = fmaxf(rm, __shfl_xor(rm, 4));
      rm = fmaxf(rm, __shfl_xor(rm, 8));
      float rs = 0.f;
#pragma unroll
      for (int j = 0; j < 4; j++) { e[j] = __expf(e[j] - rm); rs += e[j]; }
      rs += __shfl_xor(rs, 1); rs += __shfl_xor(rs, 2);
      rs += __shfl_xor(rs, 4); rs += __shfl_xor(rs, 8);
      float inv = 1.0f / rs;
#pragma unroll
      for (int j = 0; j < 4; j++) P[h][r][j * 16 + l15] = f2bf(e[j] * inv);
    }
  }
  __syncthreads();

  floatx4 o[4][2];
#pragma unroll
  for (int rb = 0; rb < 4; rb++)
#pragma unroll
    for (int db = 0; db < 2; db++) o[rb][db] = floatx4{0.f, 0.f, 0.f, 0.f};

#pragma unroll
  for (int kk = 0; kk < 2; kk++) {
    short8 pv[4];
#pragma unroll
    for (int rb = 0; rb < 4; rb++)
      pv[rb] = *(const short8*)(&P[h][rb * 16 + l15][kk * 32 + kg * 8]);
#pragma unroll
    for (int db = 0; db < 2; db++) {
      short8 vv = Vt[(db * 16 + l15) * 8 + kk * 4 + kg];
#pragma unroll
      for (int rb = 0; rb < 4; rb++)
        o[rb][db] = __builtin_amdgcn_mfma_f32_16x16x32_bf16(pv[rb], vv, o[rb][db], 0, 0, 0);
    }
  }

#pragma unroll
  for (int rb = 0; rb < 4; rb++)
#pragma unroll
    for (int db = 0; db < 2; db++)
#pragma unroll
      for (int reg = 0; reg < 4; reg++) {
        int tok = rb * 16 + kg * 4 + reg;
        int d = db * 16 + l15;
        ob[(win * 64 + tok) * 192 + h * 32 + d] = f2bf(o[rb][db][reg]);
      }
}

// ---------------- proj + residual + LN2 (full 192-col tile) ----------------
__global__ __launch_bounds__(256, 2) void k_proj(const unsigned short* __restrict__ ob,
                                                 const unsigned short* __restrict__ wp,
                                                 const float* __restrict__ pb,
                                                 const float* __restrict__ x,
                                                 const float* __restrict__ n2g,
                                                 const float* __restrict__ n2b,
                                                 float* __restrict__ out,
                                                 unsigned short* __restrict__ xn) {
  __shared__ __attribute__((aligned(16))) unsigned short smA[128 * 192];
  __shared__ __attribute__((aligned(16))) unsigned short smB[64 * 192];
  const int t = threadIdx.x;
  const int m0 = blockIdx.x * 128;
  const int lane = t & 63, w = t >> 6, kg = lane >> 4, l15 = lane & 15;

  stage_tile<12>(ob + m0 * 192, 192, smA);

  floatx4 acc[2][12];
#pragma unroll
  for (int rb = 0; rb < 2; rb++)
#pragma unroll
    for (int cb = 0; cb < 12; cb++) acc[rb][cb] = floatx4{0.f, 0.f, 0.f, 0.f};

  for (int c = 0; c < 3; c++) {
    if (c) __syncthreads();
    stage_tile<6>(wp + c * 64 * 192, 192, smB);
    asm volatile("s_waitcnt vmcnt(0)" ::: "memory");
    __syncthreads();
#pragma unroll
    for (int ks = 0; ks < 6; ks++) {
      short8 a[2], b[4];
#pragma unroll
      for (int rb = 0; rb < 2; rb++) a[rb] = frag192(smA, w * 32 + rb * 16 + l15, ks, kg);
#pragma unroll
      for (int cb = 0; cb < 4; cb++) b[cb] = frag192(smB, cb * 16 + l15, ks, kg);
#pragma unroll
      for (int rb = 0; rb < 2; rb++)
#pragma unroll
        for (int cb = 0; cb < 4; cb++)
          acc[rb][c * 4 + cb] =
              __builtin_amdgcn_mfma_f32_16x16x32_bf16(a[rb], b[cb], acc[rb][c * 4 + cb], 0, 0, 0);
    }
  }

  // epilogue: +bias +x -> out (x_new), LN -> xn
  float bias[12], gg[12], bv[12];
#pragma unroll
  for (int cb = 0; cb < 12; cb++) {
    int n = cb * 16 + l15;
    bias[cb] = pb[n];
    gg[cb] = n2g[n];
    bv[cb] = n2b[n];
  }
#pragma unroll
  for (int rb = 0; rb < 2; rb++)
#pragma unroll
    for (int reg = 0; reg < 4; reg++) {
      int m = m0 + w * 32 + rb * 16 + kg * 4 + reg;
      int win = m >> 6, tok = m & 63;
      int bd = win >> 8, bh = (win >> 4) & 15, bw = win & 15;
      int od = ((bd << 2) + (tok >> 4) + 2) & 63;
      int oh = ((bh << 2) + ((tok >> 2) & 3) + 2) & 63;
      int ow = ((bw << 2) + (tok & 3) + 2) & 63;
      int orow = (od * 64 + oh) * 64 + ow;
      const float* xr = x + orow * 192;
      float* orp = out + orow * 192;
      unsigned short* xnp = xn + orow * 192;
      float s = 0.f, ss = 0.f;
#pragma unroll
      for (int cb = 0; cb < 12; cb++) {
        float v = acc[rb][cb][reg] + bias[cb] + xr[cb * 16 + l15];
        acc[rb][cb][reg] = v;
        s += v;
        ss += v * v;
      }
      s += __shfl_xor(s, 1); ss += __shfl_xor(ss, 1);
      s += __shfl_xor(s, 2); ss += __shfl_xor(ss, 2);
      s += __shfl_xor(s, 4); ss += __shfl_xor(ss, 4);
      s += __shfl_xor(s, 8); ss += __shfl_xor(ss, 8);
      float mean = s * (1.0f / 192.0f);
      float inv = rsqrtf(ss * (1.0f / 192.0f) - mean * mean + 1e-5f);
#pragma unroll
      for (int cb = 0; cb < 12; cb++) {
        float v = acc[rb][cb][reg];
        orp[cb * 16 + l15] = v;
        xnp[cb * 16 + l15] = f2bf((v - mean) * inv * gg[cb] + bv[cb]);
      }
    }
}

// ---------------- FC1 (+GELU) ----------------
__global__ __launch_bounds__(256, 2) void k_fc1(const unsigned short* __restrict__ xn,
                                                const unsigned short* __restrict__ w1,
                                                const float* __restrict__ b1,
                                                unsigned short* __restrict__ h1, int mbase) {
  __shared__ __attribute__((aligned(16))) unsigned short smA[128 * 192];
  __shared__ __attribute__((aligned(16))) unsigned short smB[64 * 192];
  const int t = threadIdx.x;
  const int mr0 = blockIdx.x * 128;
  const int lane = t & 63, w = t >> 6, kg = lane >> 4, l15 = lane & 15;

  stage_tile<12>(xn + (mbase + mr0) * 192, 192, smA);

  short8 afr[2][6];
  floatx4 acc[2][4];
  for (int c = 0; c < 12; c++) {
    if (c) __syncthreads();
    stage_tile<6>(w1 + c * 64 * 192, 192, smB);
    asm volatile("s_waitcnt vmcnt(0)" ::: "memory");
    __syncthreads();
    if (c == 0) {
#pragma unroll
      for (int rb = 0; rb < 2; rb++)
#pragma unroll
        for (int ks = 0; ks < 6; ks++)
          afr[rb][ks] = frag192(smA, w * 32 + rb * 16 + l15, ks, kg);
    }
#pragma unroll
    for (int rb = 0; rb < 2; rb++)
#pragma unroll
      for (int cb = 0; cb < 4; cb++) acc[rb][cb] = floatx4{0.f, 0.f, 0.f, 0.f};
#pragma unroll
    for (int ks = 0; ks < 6; ks++) {
      short8 b[4];
#pragma unroll
      for (int cb = 0; cb < 4; cb++) b[cb] = frag192(smB, cb * 16 + l15, ks, kg);
#pragma unroll
      for (int rb = 0; rb < 2; rb++)
#pragma unroll
        for (int cb = 0; cb < 4; cb++)
          acc[rb][cb] = __builtin_amdgcn_mfma_f32_16x16x32_bf16(afr[rb][ks], b[cb], acc[rb][cb], 0, 0, 0);
    }
#pragma unroll
    for (int cb = 0; cb < 4; cb++) {
      int n = c * 64 + cb * 16 + l15;
      float bias = b1[n];
#pragma unroll
      for (int rb = 0; rb < 2; rb++)
#pragma unroll
        for (int reg = 0; reg < 4; reg++) {
          int mr = mr0 + w * 32 + rb * 16 + kg * 4 + reg;
          float v = acc[rb][cb][reg] + bias;
          float gl = 0.5f * v * (1.0f + erff(v * 0.70710678118654752f));
          h1[mr * 768 + n] = f2bf(gl);
        }
    }
  }
}

// ---------------- FC2 (+residual) ----------------
__global__ __launch_bounds__(256, 2) void k_fc2(const unsigned short* __restrict__ h1,
                                                const unsigned short* __restrict__ w2,
                                                const float* __restrict__ b2,
                                                float* __restrict__ out, int mbase) {
  __shared__ __attribute__((aligned(16))) unsigned short smA[128 * 192];
  __shared__ __attribute__((aligned(16))) unsigned short smB[64 * 192];
  const int t = threadIdx.x;
  const int mr0 = blockIdx.x * 128;
  const int lane = t & 63, w = t >> 6, kg = lane >> 4, l15 = lane & 15;

  floatx4 acc[2][12];
#pragma unroll
  for (int rb = 0; rb < 2; rb++)
#pragma unroll
    for (int cb = 0; cb < 12; cb++) acc[rb][cb] = floatx4{0.f, 0.f, 0.f, 0.f};

  for (int p = 0; p < 4; p++) {
    __syncthreads();
    stage_tile<12>(h1 + mr0 * 768 + p * 192, 768, smA);
    for (int c = 0; c < 3; c++) {
      if (c) __syncthreads();
      stage_tile<6>(w2 + c * 64 * 768 + p * 192, 768, smB);
      asm volatile("s_waitcnt vmcnt(0)" ::: "memory");
      __syncthreads();
#pragma unroll
      for (int ks = 0; ks < 6; ks++) {
        short8 a[2], b[4];
#pragma unroll
        for (int rb = 0; rb < 2; rb++) a[rb] = frag192(smA, w * 32 + rb * 16 + l15, ks, kg);
#pragma unroll
        for (int cb = 0; cb < 4; cb++) b[cb] = frag192(smB, cb * 16 + l15, ks, kg);
#pragma unroll
        for (int rb = 0; rb < 2; rb++)
#pragma unroll
          for (int cb = 0; cb < 4; cb++)
            acc[rb][c * 4 + cb] =
                __builtin_amdgcn_mfma_f32_16x16x32_bf16(a[rb], b[cb], acc[rb][c * 4 + cb], 0, 0, 0);
      }
    }
  }

#pragma unroll
  for (int cb = 0; cb < 12; cb++) {
    int n = cb * 16 + l15;
    float bias = b2[n];
#pragma unroll
    for (int rb = 0; rb < 2; rb++)
#pragma unroll
      for (int reg = 0; reg < 4; reg++) {
        int m = mbase + mr0 + w * 32 + rb * 16 + kg * 4 + reg;
        out[m * 192 + n] = out[m * 192 + n] + acc[rb][cb][reg] + bias;
      }
  }
}

// ---------------- launch ----------------
extern "C" void kernel_launch(void* const* d_in, const int* in_sizes, int n_in,
                              void* d_out, int out_size, void* d_ws, size_t ws_size,
                              hipStream_t stream) {
  const float* x     = (const float*)d_in[0];
  const float* n1g   = (const float*)d_in[2];
  const float* n1b   = (const float*)d_in[3];
  const float* qkvw  = (const float*)d_in[4];
  const float* qkvb  = (const float*)d_in[5];
  const float* rpb   = (const float*)d_in[6];
  const float* projw = (const float*)d_in[7];
  const float* projb = (const float*)d_in[8];
  const float* n2g   = (const float*)d_in[9];
  const float* n2b   = (const float*)d_in[10];
  const float* fc1w  = (const float*)d_in[11];
  const float* fc1b  = (const float*)d_in[12];
  const float* fc2w  = (const float*)d_in[13];
  const float* fc2b  = (const float*)d_in[14];
  float* out = (float*)d_out;
  char* ws = (char*)d_ws;

  unsigned short* ob = (unsigned short*)(ws);                // attn out (window order)
  unsigned short* qb = (unsigned short*)(ws + 100663296);    // -> h1 chunk after attn
  unsigned short* kb = (unsigned short*)(ws + 201326592);    // -> xn after attn
  unsigned short* vb = (unsigned short*)(ws + 301989888);
  unsigned short* h1 = qb;
  unsigned short* xn = kb;
  unsigned short* wq = (unsigned short*)(ws + 402653184);
  unsigned short* wp = wq + 110592;
  unsigned short* w1 = wp + 36864;
  unsigned short* w2 = w1 + 147456;
  float* btab = (float*)(ws + 402653184 + 884736);

  k_wcvt<<<dim3(432), 256, 0, stream>>>(qkvw, wq, 110592);
  k_wcvt<<<dim3(144), 256, 0, stream>>>(projw, wp, 36864);
  k_wcvt<<<dim3(576), 256, 0, stream>>>(fc1w, w1, 147456);
  k_wcvt<<<dim3(576), 256, 0, stream>>>(fc2w, w2, 147456);
  k_bias<<<dim3(96), 256, 0, stream>>>(rpb, btab);

  k_qkv<<<dim3(2048), 256, 0, stream>>>(x, n1g, n1b, wq, qkvb, qb, kb, vb);
  k_attn<<<dim3(4096), 384, 0, stream>>>(qb, kb, vb, btab, ob);
  k_proj<<<dim3(2048), 256, 0, stream>>>(ob, wp, projb, x, n2g, n2b, out, xn);
  for (int c = 0; c < 4; c++) {
    k_fc1<<<dim3(512), 256, 0, stream>>>(xn, w1, fc1b, h1, c * 65536);
    k_fc2<<<dim3(512), 256, 0, stream>>>(h1, w2, fc2b, out, c * 65536);
  }
}